// Round 6
// baseline (1283.382 us; speedup 1.0000x reference)
//
#include <hip/hip_runtime.h>

#define NT 64
#define DIMC 256
#define NHEADS 8
#define NWIN 2048
#define TOPK_ 51
#define SCALE_ 0.17677669529663687f

// Split-bf16 GEMM scheme: fp32 value v -> hi=bf16(v), lo=bf16(v-hi).
// v*w ~= hi_v*hi_w + hi_v*lo_w + lo_v*hi_w  (3 MFMAs, fp32 accum, rel err ~1e-5).
//
// v_mfma_f32_16x16x32_bf16 lane mappings (verified by r3/r4 PASS):
//   A frag (8 bf16): A[l%16][8*(l/16)+j]
//   B frag (8 bf16): B[8*(l/16)+j][l%16]
//   D (4 f32):       D[4*(l/16)+r][l%16]
//
// ws layout (bytes): unchanged
//   [0, 393216)        wqhi  [393216, 786432) wqlo   (qkv weights, frag-packed [ct=48][ks=8][lane=64][8])
//   [786432, 917504)   wphi  [917504, 1048576) wplo  (proj weights, [ct=16][ks=8][lane=64][8])
//   [1048576, 2097152) masks: 2048 x 64 u64

typedef short bf16x8 __attribute__((ext_vector_type(8)));
typedef float f32x4 __attribute__((ext_vector_type(4)));

#define MFMA16 __builtin_amdgcn_mfma_f32_16x16x32_bf16

__device__ __forceinline__ unsigned short f2bf(float f) {
    unsigned u = __float_as_uint(f);
    u += 0x7fffu + ((u >> 16) & 1u);           // RNE
    return (unsigned short)(u >> 16);
}
__device__ __forceinline__ float bf2f(unsigned short h) {
    return __uint_as_float(((unsigned)h) << 16);
}
__device__ __forceinline__ void cvt4(const float4& v, ushort4& h, ushort4& lo) {
    h.x = f2bf(v.x); h.y = f2bf(v.y); h.z = f2bf(v.z); h.w = f2bf(v.w);
    lo.x = f2bf(v.x - bf2f(h.x)); lo.y = f2bf(v.y - bf2f(h.y));
    lo.z = f2bf(v.z - bf2f(h.z)); lo.w = f2bf(v.w - bf2f(h.w));
}

// ---------------- kernel 0: weight split + fragment pack (unchanged, passed) ----------------
__global__ __launch_bounds__(256) void k_prep(
    const float* __restrict__ qkv_w, const float* __restrict__ proj_w,
    unsigned short* __restrict__ wqhi, unsigned short* __restrict__ wqlo,
    unsigned short* __restrict__ wphi, unsigned short* __restrict__ wplo)
{
    int e = blockIdx.x * 256 + threadIdx.x;      // [0, 262144)
    float v; unsigned short* hi; unsigned short* lo; int di;
    if (e < 196608) {
        int j = e & 7, l = (e >> 3) & 63, ks = (e >> 9) & 7, ct = e >> 12;  // ct 0..47
        int o = ct * 16 + (l & 15);
        int k = ks * 32 + 8 * (l >> 4) + j;
        v = qkv_w[o * 256 + k]; hi = wqhi; lo = wqlo; di = e;
    } else {
        int e2 = e - 196608;
        int j = e2 & 7, l = (e2 >> 3) & 63, ks = (e2 >> 9) & 7, ct = e2 >> 12; // ct 0..15
        int o = ct * 16 + (l & 15);
        int k = ks * 32 + 8 * (l >> 4) + j;
        v = proj_w[o * 256 + k]; hi = wphi; lo = wplo; di = e2;
    }
    unsigned short h = f2bf(v);
    hi[di] = h;
    lo[di] = f2bf(v - bf2f(h));
}

// ---------------- kernel 1: var self-similarity + top-51 mask (512 thr) ----------------
__global__ __launch_bounds__(512) void k_modulation(
    const float* __restrict__ var, unsigned long long* __restrict__ masks)
{
    __shared__ float vs[64][257];                 // padded, conflict-free
    __shared__ float ss[64][65];
    __shared__ alignas(8) unsigned char bits[64][8];
    const int b = blockIdx.x, t = threadIdx.x;

    const float* vp = var + (size_t)b * (NT * DIMC);
    #pragma unroll
    for (int i = 0; i < 8; ++i) {
        int idx = t + i * 512;                    // float4 index < 4096
        float4 v = reinterpret_cast<const float4*>(vp)[idx];
        int n = idx >> 6, k = (idx & 63) << 2;
        vs[n][k + 0] = v.x; vs[n][k + 1] = v.y; vs[n][k + 2] = v.z; vs[n][k + 3] = v.w;
    }
    __syncthreads();

    // var_self: 2x4 tile per thread (512 threads cover 64x64)
    {
        const int r0 = (t >> 4) << 1, c0 = (t & 15) << 2;
        float acc[2][4];
        #pragma unroll
        for (int i = 0; i < 2; ++i)
            #pragma unroll
            for (int j = 0; j < 4; ++j) acc[i][j] = 0.f;
        #pragma unroll 4
        for (int k = 0; k < 256; ++k) {
            const float a0 = vs[r0][k], a1 = vs[r0 + 1][k];
            float bv[4];
            #pragma unroll
            for (int j = 0; j < 4; ++j) bv[j] = vs[c0 + j][k];
            #pragma unroll
            for (int j = 0; j < 4; ++j) { acc[0][j] += a0 * bv[j]; acc[1][j] += a1 * bv[j]; }
        }
        #pragma unroll
        for (int i = 0; i < 2; ++i)
            #pragma unroll
            for (int j = 0; j < 4; ++j) ss[r0 + i][c0 + j] = acc[i][j];
    }
    __syncthreads();

    // rank; top-51 with jax.lax.top_k tie semantics (stable: lower index wins)
    {
        const int n = t >> 3, q = t & 7, mb = q * 8;
        float sv[8];
        int cnt[8];
        #pragma unroll
        for (int j = 0; j < 8; ++j) { sv[j] = ss[n][mb + j]; cnt[j] = 0; }
        for (int p = 0; p < 64; ++p) {
            const float vv = ss[n][p];
            #pragma unroll
            for (int j = 0; j < 8; ++j)
                cnt[j] += (vv > sv[j] || (vv == sv[j] && p < mb + j)) ? 1 : 0;
        }
        unsigned w = 0;
        #pragma unroll
        for (int j = 0; j < 8; ++j) if (cnt[j] < TOPK_) w |= (1u << j);
        bits[n][q] = (unsigned char)w;
    }
    __syncthreads();
    if (t < 64)
        masks[(size_t)b * 64 + t] = *reinterpret_cast<const unsigned long long*>(&bits[t][0]);
}

// ---------------- kernel 2: fully fused qkv -> attention -> out-projection ----------------
// Per pass p: qkv GEMM for heads (2p,2p+1) -> QK^T -> softmax -> PV -> och LDS chunk
// -> rank-64 partial proj GEMM accumulated in registers. Epilogue: bias + store out.
__global__ __launch_bounds__(512) void k_attn(
    const float* __restrict__ x,
    const float* __restrict__ qkv_b,
    const float* __restrict__ proj_b,
    const float* __restrict__ rpb_table,
    const unsigned short* __restrict__ wqhi,
    const unsigned short* __restrict__ wqlo,
    const unsigned short* __restrict__ wphi,
    const unsigned short* __restrict__ wplo,
    const unsigned long long* __restrict__ masks,
    float* __restrict__ out)
{
    // smem map (bytes), all offsets 16B-aligned:
    //   [0,33792)        xhi [64][264]
    //   [33792,67584)    xlo [64][264]
    //   [67584,76800)    qhi [64][72]   \ aliased after QK^T by
    //   [76800,86016)    qlo [64][72]    > phi [2][64][72] (67584..86016)
    //   [86016,95232)    khi [64][72]    > plo [2][64][72] (86016..104448)
    //   [95232,104448)   klo [64][72]   /
    //   [104448,113664)  vThi [2][32][72]
    //   [113664,122880)  vTlo [2][32][72]
    //   [122880,132096)  ohi [64][72]   (per-pass attn-out chunk, bf16 hi)
    //   [132096,141312)  olo [64][72]
    //   [141312,148512)  rpb_l [1800] f32
    //   [148512,149024)  mask_l [64] u64
    __shared__ alignas(16) char smem[149024];
    unsigned short* xhi  = (unsigned short*)(smem);
    unsigned short* xlo  = (unsigned short*)(smem + 33792);
    unsigned short* qhi  = (unsigned short*)(smem + 67584);
    unsigned short* qlo  = (unsigned short*)(smem + 76800);
    unsigned short* khi  = (unsigned short*)(smem + 86016);
    unsigned short* klo  = (unsigned short*)(smem + 95232);
    unsigned short* phi  = (unsigned short*)(smem + 67584);   // [2][64][72]
    unsigned short* plo  = (unsigned short*)(smem + 86016);   // [2][64][72]
    unsigned short* vThi = (unsigned short*)(smem + 104448);  // [2][32][72]
    unsigned short* vTlo = (unsigned short*)(smem + 113664);
    unsigned short* ohi  = (unsigned short*)(smem + 122880);  // [64][72]
    unsigned short* olo  = (unsigned short*)(smem + 132096);
    float* rpb_l = (float*)(smem + 141312);
    unsigned long long* mask_l = (unsigned long long*)(smem + 148512);

    const int b = blockIdx.x, t = threadIdx.x;
    const int l = t & 63, l15 = l & 15, lg = l >> 4;
    const int w = __builtin_amdgcn_readfirstlane(t >> 6);
    // qkv-GEMM role
    const int g_rt0 = 2 * (w & 1);       // row-tiles {g_rt0, g_rt0+1}
    const int g_pc0 = 3 * (w >> 1);      // pass-col-tiles {g_pc0..g_pc0+2} of 12
    // attention role
    const int hg = w >> 2;               // local head 0/1
    const int rs = w & 3;                // S row strip

    // ---- stage x -> bf16 hi/lo in LDS (once), plus rpb + masks ----
    const float* xp = x + (size_t)b * (NT * DIMC);
    #pragma unroll
    for (int i = 0; i < 8; ++i) {
        int idx = t + i * 512;             // float4 index < 4096
        float4 v = reinterpret_cast<const float4*>(xp)[idx];
        int n = idx >> 6, kq = (idx & 63) << 2;
        ushort4 h, lo;
        cvt4(v, h, lo);
        *reinterpret_cast<ushort4*>(&xhi[n * 264 + kq]) = h;
        *reinterpret_cast<ushort4*>(&xlo[n * 264 + kq]) = lo;
    }
    for (int i = t; i < 1800; i += 512) rpb_l[i] = rpb_table[i];
    if (t < 64) mask_l[t] = masks[(size_t)b * 64 + t];

    // persistent proj accumulator: wave owns col-tiles {2w, 2w+1}, rows all 64
    f32x4 accp[2][4];
    #pragma unroll
    for (int c = 0; c < 2; ++c) {
        const float bv = proj_b[(2 * w + c) * 16 + l15];
        #pragma unroll
        for (int rt = 0; rt < 4; ++rt) accp[c][rt] = (f32x4){bv, bv, bv, bv};
    }
    __syncthreads();

    for (int pass = 0; pass < 4; ++pass) {
        // ---- phase 1: qkv GEMM for heads (2*pass, 2*pass+1); A-frags from LDS ----
        f32x4 acc[3][2];
        #pragma unroll
        for (int c = 0; c < 3; ++c) {
            const int pc = g_pc0 + c, mat = pc >> 2, within = pc & 3;
            const float bv = qkv_b[mat * 256 + (4 * pass + within) * 16 + l15];
            acc[c][0] = (f32x4){bv, bv, bv, bv};
            acc[c][1] = (f32x4){bv, bv, bv, bv};
        }
        for (int ks = 0; ks < 8; ++ks) {
            const int a0 = (g_rt0 * 16 + l15) * 264 + ks * 32 + lg * 8;
            const int a1 = a0 + 16 * 264;
            const bf16x8 ah0 = *reinterpret_cast<const bf16x8*>(&xhi[a0]);
            const bf16x8 al0 = *reinterpret_cast<const bf16x8*>(&xlo[a0]);
            const bf16x8 ah1 = *reinterpret_cast<const bf16x8*>(&xhi[a1]);
            const bf16x8 al1 = *reinterpret_cast<const bf16x8*>(&xlo[a1]);
            #pragma unroll
            for (int c = 0; c < 3; ++c) {
                const int pc = g_pc0 + c, mat = pc >> 2, within = pc & 3;
                const int ct = mat * 16 + 4 * pass + within;
                const bf16x8 bh = *reinterpret_cast<const bf16x8*>(wqhi + ct * 4096 + ks * 512 + l * 8);
                const bf16x8 bl = *reinterpret_cast<const bf16x8*>(wqlo + ct * 4096 + ks * 512 + l * 8);
                acc[c][0] = MFMA16(ah0, bh, acc[c][0], 0, 0, 0);
                acc[c][0] = MFMA16(ah0, bl, acc[c][0], 0, 0, 0);
                acc[c][0] = MFMA16(al0, bh, acc[c][0], 0, 0, 0);
                acc[c][1] = MFMA16(ah1, bh, acc[c][1], 0, 0, 0);
                acc[c][1] = MFMA16(ah1, bl, acc[c][1], 0, 0, 0);
                acc[c][1] = MFMA16(al1, bh, acc[c][1], 0, 0, 0);
            }
        }
        // write q/k (row-major, +SCALE on q) and v transposed, all bf16 hi/lo
        #pragma unroll
        for (int c = 0; c < 3; ++c) {
            const int pc = g_pc0 + c, mat = pc >> 2, within = pc & 3;
            const int hh = within >> 1, dh = within & 1;
            #pragma unroll
            for (int rtl = 0; rtl < 2; ++rtl) {
                const int tok0 = (g_rt0 + rtl) * 16 + 4 * lg;
                #pragma unroll
                for (int r = 0; r < 4; ++r) {
                    float val = acc[c][rtl][r];
                    const int tok = tok0 + r;
                    if (mat == 0) {
                        val *= SCALE_;
                        const unsigned short hv = f2bf(val);
                        qhi[tok * 72 + hh * 32 + dh * 16 + l15] = hv;
                        qlo[tok * 72 + hh * 32 + dh * 16 + l15] = f2bf(val - bf2f(hv));
                    } else if (mat == 1) {
                        const unsigned short hv = f2bf(val);
                        khi[tok * 72 + hh * 32 + dh * 16 + l15] = hv;
                        klo[tok * 72 + hh * 32 + dh * 16 + l15] = f2bf(val - bf2f(hv));
                    } else {
                        const int d = dh * 16 + l15;
                        const unsigned short hv = f2bf(val);
                        vThi[hh * 2304 + d * 72 + tok] = hv;
                        vTlo[hh * 2304 + d * 72 + tok] = f2bf(val - bf2f(hv));
                    }
                }
            }
        }
        __syncthreads();   // (1) q/k/vT ready

        // ---- phase 2: QK^T (head h = 2*pass + hg, rows rs*16..+16) ----
        const int h = 2 * pass + hg;
        const bf16x8 aqh = *reinterpret_cast<const bf16x8*>(&qhi[(rs * 16 + l15) * 72 + hg * 32 + lg * 8]);
        const bf16x8 aql = *reinterpret_cast<const bf16x8*>(&qlo[(rs * 16 + l15) * 72 + hg * 32 + lg * 8]);
        f32x4 s[4];
        #pragma unroll
        for (int cs = 0; cs < 4; ++cs) {
            const bf16x8 bkh = *reinterpret_cast<const bf16x8*>(&khi[(cs * 16 + l15) * 72 + hg * 32 + lg * 8]);
            const bf16x8 bkl = *reinterpret_cast<const bf16x8*>(&klo[(cs * 16 + l15) * 72 + hg * 32 + lg * 8]);
            f32x4 z = (f32x4){0.f, 0.f, 0.f, 0.f};
            z = MFMA16(aqh, bkh, z, 0, 0, 0);
            z = MFMA16(aqh, bkl, z, 0, 0, 0);
            z = MFMA16(aql, bkh, z, 0, 0, 0);
            s[cs] = z;
        }
        // modulation + rpb + softmax (exact fp32 semantics)
        const int srow0 = rs * 16 + 4 * lg;
        unsigned long long mw[4];
        #pragma unroll
        for (int r = 0; r < 4; ++r) mw[r] = mask_l[srow0 + r];
        float pbuf[4][4], mx[4], sm[4], inv[4];
        #pragma unroll
        for (int r = 0; r < 4; ++r) mx[r] = -1e30f;
        #pragma unroll
        for (int cs = 0; cs < 4; ++cs) {
            const int scol = cs * 16 + l15;
            #pragma unroll
            for (int r = 0; r < 4; ++r) {
                const int srow = srow0 + r;
                float sv = s[cs][r];
                sv *= ((mw[r] >> scol) & 1ull) ? 1.0f : 1.2f;
                const int ridx = ((srow >> 3) - (scol >> 3) + 7) * 15 + ((srow & 7) - (scol & 7) + 7);
                sv += rpb_l[ridx * NHEADS + h];
                pbuf[r][cs] = sv;
                mx[r] = fmaxf(mx[r], sv);
            }
        }
        #pragma unroll
        for (int r = 0; r < 4; ++r) {
            mx[r] = fmaxf(mx[r], __shfl_xor(mx[r], 1));
            mx[r] = fmaxf(mx[r], __shfl_xor(mx[r], 2));
            mx[r] = fmaxf(mx[r], __shfl_xor(mx[r], 4));
            mx[r] = fmaxf(mx[r], __shfl_xor(mx[r], 8));
            sm[r] = 0.f;
        }
        #pragma unroll
        for (int cs = 0; cs < 4; ++cs)
            #pragma unroll
            for (int r = 0; r < 4; ++r) {
                pbuf[r][cs] = __expf(pbuf[r][cs] - mx[r]);
                sm[r] += pbuf[r][cs];
            }
        #pragma unroll
        for (int r = 0; r < 4; ++r) {
            sm[r] += __shfl_xor(sm[r], 1);
            sm[r] += __shfl_xor(sm[r], 2);
            sm[r] += __shfl_xor(sm[r], 4);
            sm[r] += __shfl_xor(sm[r], 8);
            inv[r] = 1.f / sm[r];
        }
        __syncthreads();   // (2) q/k reads done; P may overwrite that space

        #pragma unroll
        for (int cs = 0; cs < 4; ++cs) {
            const int scol = cs * 16 + l15;
            #pragma unroll
            for (int r = 0; r < 4; ++r) {
                const float pp = pbuf[r][cs] * inv[r];
                const unsigned short ph = f2bf(pp);
                phi[hg * 4608 + (srow0 + r) * 72 + scol] = ph;
                plo[hg * 4608 + (srow0 + r) * 72 + scol] = f2bf(pp - bf2f(ph));
            }
        }
        __syncthreads();   // (3) P ready

        // ---- phase 3: PV -> och chunk (rows rs*16..+16, local cols hg*32..+32) ----
        #pragma unroll
        for (int dt = 0; dt < 2; ++dt) {
            f32x4 o_ = (f32x4){0.f, 0.f, 0.f, 0.f};
            #pragma unroll
            for (int k2 = 0; k2 < 2; ++k2) {
                const bf16x8 pah = *reinterpret_cast<const bf16x8*>(&phi[hg * 4608 + (rs * 16 + l15) * 72 + k2 * 32 + lg * 8]);
                const bf16x8 pal = *reinterpret_cast<const bf16x8*>(&plo[hg * 4608 + (rs * 16 + l15) * 72 + k2 * 32 + lg * 8]);
                const bf16x8 vbh = *reinterpret_cast<const bf16x8*>(&vThi[hg * 2304 + (dt * 16 + l15) * 72 + k2 * 32 + lg * 8]);
                const bf16x8 vbl = *reinterpret_cast<const bf16x8*>(&vTlo[hg * 2304 + (dt * 16 + l15) * 72 + k2 * 32 + lg * 8]);
                o_ = MFMA16(pah, vbh, o_, 0, 0, 0);
                o_ = MFMA16(pah, vbl, o_, 0, 0, 0);
                o_ = MFMA16(pal, vbh, o_, 0, 0, 0);
            }
            #pragma unroll
            for (int r = 0; r < 4; ++r) {
                const float ov = o_[r];
                const unsigned short hv = f2bf(ov);
                const int oo = (srow0 + r) * 72 + hg * 32 + dt * 16 + l15;
                ohi[oo] = hv;
                olo[oo] = f2bf(ov - bf2f(hv));
            }
        }
        __syncthreads();   // (4) och ready

        // ---- phase 4: rank-64 partial proj GEMM; C-slice ks = {2*pass, 2*pass+1} ----
        #pragma unroll
        for (int kk = 0; kk < 2; ++kk) {
            const int ks = 2 * pass + kk;
            bf16x8 bh[2], bl[2];
            #pragma unroll
            for (int c = 0; c < 2; ++c) {
                const int ct = 2 * w + c;
                bh[c] = *reinterpret_cast<const bf16x8*>(wphi + ct * 4096 + ks * 512 + l * 8);
                bl[c] = *reinterpret_cast<const bf16x8*>(wplo + ct * 4096 + ks * 512 + l * 8);
            }
            #pragma unroll
            for (int rt = 0; rt < 4; ++rt) {
                const int ao = (rt * 16 + l15) * 72 + kk * 32 + lg * 8;
                const bf16x8 ah = *reinterpret_cast<const bf16x8*>(&ohi[ao]);
                const bf16x8 al = *reinterpret_cast<const bf16x8*>(&olo[ao]);
                #pragma unroll
                for (int c = 0; c < 2; ++c) {
                    accp[c][rt] = MFMA16(ah, bh[c], accp[c][rt], 0, 0, 0);
                    accp[c][rt] = MFMA16(ah, bl[c], accp[c][rt], 0, 0, 0);
                    accp[c][rt] = MFMA16(al, bh[c], accp[c][rt], 0, 0, 0);
                }
            }
        }
        __syncthreads();   // (5) och/p/vT reads done before next pass overwrites
    }

    // ---- epilogue: store projected output (same pattern as verified k_proj) ----
    float* base = out + (size_t)b * (NT * DIMC);
    {
        const int rowo = 4 * lg;
        #pragma unroll
        for (int c = 0; c < 2; ++c) {
            const int col = (2 * w + c) * 16 + l15;
            #pragma unroll
            for (int rt = 0; rt < 4; ++rt) {
                #pragma unroll
                for (int r = 0; r < 4; ++r)
                    base[(rt * 16 + rowo + r) * 256 + col] = accp[c][rt][r];
            }
        }
    }
}

extern "C" void kernel_launch(void* const* d_in, const int* in_sizes, int n_in,
                              void* d_out, int out_size, void* d_ws, size_t ws_size,
                              hipStream_t stream)
{
    const float* x      = (const float*)d_in[0];
    const float* var    = (const float*)d_in[1];
    const float* qkv_w  = (const float*)d_in[2];
    const float* qkv_b  = (const float*)d_in[3];
    const float* proj_w = (const float*)d_in[4];
    const float* proj_b = (const float*)d_in[5];
    const float* rpb    = (const float*)d_in[6];
    float* out = (float*)d_out;

    unsigned short* wqhi = (unsigned short*)d_ws;          // 196608
    unsigned short* wqlo = wqhi + 196608;                  // 196608
    unsigned short* wphi = wqlo + 196608;                  // 65536
    unsigned short* wplo = wphi + 65536;                   // 65536
    unsigned long long* masks = (unsigned long long*)((char*)d_ws + 1048576);

    k_prep      <<<1024, 256, 0, stream>>>(qkv_w, proj_w, wqhi, wqlo, wphi, wplo);
    k_modulation<<<NWIN, 512, 0, stream>>>(var, masks);
    k_attn      <<<NWIN, 512, 0, stream>>>(x, qkv_b, proj_b, rpb, wqhi, wqlo, wphi, wplo, masks, out);
}

// Round 7
// 1210.095 us; speedup vs baseline: 1.0606x; 1.0606x over previous
//
#include <hip/hip_runtime.h>

#define NT 64
#define DIMC 256
#define NHEADS 8
#define NWIN 2048
#define TOPK_ 51
#define SCALE_ 0.17677669529663687f

// Split-bf16 GEMM scheme: fp32 value v -> hi=bf16(v), lo=bf16(v-hi).
// v*w ~= hi_v*hi_w + hi_v*lo_w + lo_v*hi_w  (3 MFMAs, fp32 accum, rel err ~1e-5).
//
// v_mfma_f32_16x16x32_bf16 lane mappings (verified by r3/r4/r6 PASS):
//   A frag (8 bf16): A[l%16][8*(l/16)+j]
//   B frag (8 bf16): B[8*(l/16)+j][l%16]
//   D (4 f32):       D[4*(l/16)+r][l%16]
//
// ws layout (bytes):
//   [0, 393216)        wqhi  [393216, 786432) wqlo   (qkv weights, frag-packed [ct=48][ks=8][lane=64][8])
//   [786432, 917504)   wphi  [917504, 1048576) wplo  (proj weights, [ct=16][ks=8][lane=64][8])
//   [1048576, 2097152) masks: 2048 x 64 u64
//   [2097152, 69206016)    xsh: x hi bf16, row-major [2048][64][256]   (only if ws_size allows)
//   [69206016, 136314880)  xsl: x lo bf16
#define PRESPLIT_NEED 136314880ull

typedef short bf16x8 __attribute__((ext_vector_type(8)));
typedef float f32x4 __attribute__((ext_vector_type(4)));

#define MFMA16 __builtin_amdgcn_mfma_f32_16x16x32_bf16

__device__ __forceinline__ unsigned short f2bf(float f) {
    unsigned u = __float_as_uint(f);
    u += 0x7fffu + ((u >> 16) & 1u);           // RNE
    return (unsigned short)(u >> 16);
}
__device__ __forceinline__ float bf2f(unsigned short h) {
    return __uint_as_float(((unsigned)h) << 16);
}
__device__ __forceinline__ void cvt4(const float4& v, ushort4& h, ushort4& lo) {
    h.x = f2bf(v.x); h.y = f2bf(v.y); h.z = f2bf(v.z); h.w = f2bf(v.w);
    lo.x = f2bf(v.x - bf2f(h.x)); lo.y = f2bf(v.y - bf2f(h.y));
    lo.z = f2bf(v.z - bf2f(h.z)); lo.w = f2bf(v.w - bf2f(h.w));
}
__device__ __forceinline__ void cvt8(const float* v, bf16x8& h, bf16x8& lo) {
#pragma unroll
    for (int j = 0; j < 8; ++j) {
        unsigned short hh = f2bf(v[j]);
        h[j] = (short)hh;
        lo[j] = (short)f2bf(v[j] - bf2f(hh));
    }
}

// ---------------- kernel 0: weight split + fragment pack (unchanged, passed) ----------------
__global__ __launch_bounds__(256) void k_prep(
    const float* __restrict__ qkv_w, const float* __restrict__ proj_w,
    unsigned short* __restrict__ wqhi, unsigned short* __restrict__ wqlo,
    unsigned short* __restrict__ wphi, unsigned short* __restrict__ wplo)
{
    int e = blockIdx.x * 256 + threadIdx.x;      // [0, 262144)
    float v; unsigned short* hi; unsigned short* lo; int di;
    if (e < 196608) {
        int j = e & 7, l = (e >> 3) & 63, ks = (e >> 9) & 7, ct = e >> 12;  // ct 0..47
        int o = ct * 16 + (l & 15);
        int k = ks * 32 + 8 * (l >> 4) + j;
        v = qkv_w[o * 256 + k]; hi = wqhi; lo = wqlo; di = e;
    } else {
        int e2 = e - 196608;
        int j = e2 & 7, l = (e2 >> 3) & 63, ks = (e2 >> 9) & 7, ct = e2 >> 12; // ct 0..15
        int o = ct * 16 + (l & 15);
        int k = ks * 32 + 8 * (l >> 4) + j;
        v = proj_w[o * 256 + k]; hi = wphi; lo = wplo; di = e2;
    }
    unsigned short h = f2bf(v);
    hi[di] = h;
    lo[di] = f2bf(v - bf2f(h));
}

// ---------------- kernel 0b: x split into global bf16 hi/lo (row-major) ----------------
__global__ __launch_bounds__(256) void k_xsplit(
    const float* __restrict__ x,
    unsigned short* __restrict__ xsh, unsigned short* __restrict__ xsl)
{
    const int t = threadIdx.x;
    #pragma unroll
    for (int i = 0; i < 8; ++i) {
        const size_t idx = (size_t)blockIdx.x * 2048 + i * 256 + t;   // float4 index
        float4 v = reinterpret_cast<const float4*>(x)[idx];
        ushort4 h, lo;
        cvt4(v, h, lo);
        reinterpret_cast<ushort4*>(xsh)[idx] = h;
        reinterpret_cast<ushort4*>(xsl)[idx] = lo;
    }
}

// ---------------- kernel 1: var self-similarity + top-51 mask (512 thr, passed r6) ----------------
__global__ __launch_bounds__(512) void k_modulation(
    const float* __restrict__ var, unsigned long long* __restrict__ masks)
{
    __shared__ float vs[64][257];                 // padded, conflict-free
    __shared__ float ss[64][65];
    __shared__ alignas(8) unsigned char bits[64][8];
    const int b = blockIdx.x, t = threadIdx.x;

    const float* vp = var + (size_t)b * (NT * DIMC);
    #pragma unroll
    for (int i = 0; i < 8; ++i) {
        int idx = t + i * 512;                    // float4 index < 4096
        float4 v = reinterpret_cast<const float4*>(vp)[idx];
        int n = idx >> 6, k = (idx & 63) << 2;
        vs[n][k + 0] = v.x; vs[n][k + 1] = v.y; vs[n][k + 2] = v.z; vs[n][k + 3] = v.w;
    }
    __syncthreads();

    // var_self: 2x4 tile per thread (512 threads cover 64x64)
    {
        const int r0 = (t >> 4) << 1, c0 = (t & 15) << 2;
        float acc[2][4];
        #pragma unroll
        for (int i = 0; i < 2; ++i)
            #pragma unroll
            for (int j = 0; j < 4; ++j) acc[i][j] = 0.f;
        #pragma unroll 4
        for (int k = 0; k < 256; ++k) {
            const float a0 = vs[r0][k], a1 = vs[r0 + 1][k];
            float bv[4];
            #pragma unroll
            for (int j = 0; j < 4; ++j) bv[j] = vs[c0 + j][k];
            #pragma unroll
            for (int j = 0; j < 4; ++j) { acc[0][j] += a0 * bv[j]; acc[1][j] += a1 * bv[j]; }
        }
        #pragma unroll
        for (int i = 0; i < 2; ++i)
            #pragma unroll
            for (int j = 0; j < 4; ++j) ss[r0 + i][c0 + j] = acc[i][j];
    }
    __syncthreads();

    // rank; top-51 with jax.lax.top_k tie semantics (stable: lower index wins)
    {
        const int n = t >> 3, q = t & 7, mb = q * 8;
        float sv[8];
        int cnt[8];
        #pragma unroll
        for (int j = 0; j < 8; ++j) { sv[j] = ss[n][mb + j]; cnt[j] = 0; }
        for (int p = 0; p < 64; ++p) {
            const float vv = ss[n][p];
            #pragma unroll
            for (int j = 0; j < 8; ++j)
                cnt[j] += (vv > sv[j] || (vv == sv[j] && p < mb + j)) ? 1 : 0;
        }
        unsigned w = 0;
        #pragma unroll
        for (int j = 0; j < 8; ++j) if (cnt[j] < TOPK_) w |= (1u << j);
        bits[n][q] = (unsigned char)w;
    }
    __syncthreads();
    if (t < 64)
        masks[(size_t)b * 64 + t] = *reinterpret_cast<const unsigned long long*>(&bits[t][0]);
}

// ---------------- kernel 2: MFMA qkv -> MFMA attention (r4 structure, 61.5 KB LDS) ----------------
// MODE 0: A-frags from global fp32 x + cvt (r4-verified). MODE 1: from pre-split bf16 xsh/xsl.
template<int MODE>
__global__ __launch_bounds__(512) void k_attn(
    const float* __restrict__ x,
    const unsigned short* __restrict__ xsh,
    const unsigned short* __restrict__ xsl,
    const float* __restrict__ qkv_b,
    const float* __restrict__ rpb_table,
    const unsigned short* __restrict__ wqhi,
    const unsigned short* __restrict__ wqlo,
    const unsigned long long* __restrict__ masks,
    float* __restrict__ aout)
{
    // smem map (bytes):
    //   [0,9216)       qhi [64][72]   \ aliased after QK^T by
    //   [9216,18432)   qlo [64][72]    > phi [2][64][72] (0..18432)
    //   [18432,27648)  khi [64][72]    > plo [2][64][72] (18432..36864)
    //   [27648,36864)  klo [64][72]   /
    //   [36864,46080)  vThi [2][32][72]
    //   [46080,55296)  vTlo [2][32][72]
    //   [55296,62496)  rpb_l [1800] f32
    //   [62496,63008)  mask_l [64] u64
    __shared__ alignas(16) char smem[63008];
    unsigned short* qhi  = (unsigned short*)(smem);
    unsigned short* qlo  = (unsigned short*)(smem + 9216);
    unsigned short* khi  = (unsigned short*)(smem + 18432);
    unsigned short* klo  = (unsigned short*)(smem + 27648);
    unsigned short* phi  = (unsigned short*)(smem);           // [2][64][72]
    unsigned short* plo  = (unsigned short*)(smem + 18432);   // [2][64][72]
    unsigned short* vThi = (unsigned short*)(smem + 36864);   // [2][32][72]
    unsigned short* vTlo = (unsigned short*)(smem + 46080);
    float* rpb_l = (float*)(smem + 55296);
    unsigned long long* mask_l = (unsigned long long*)(smem + 62496);

    const int b = blockIdx.x, t = threadIdx.x;
    const int l = t & 63, l15 = l & 15, lg = l >> 4;
    const int w = __builtin_amdgcn_readfirstlane(t >> 6);
    // qkv-GEMM role
    const int g_rt0 = 2 * (w & 1);       // row-tiles {g_rt0, g_rt0+1}
    const int g_pc0 = 3 * (w >> 1);      // pass-col-tiles {g_pc0..g_pc0+2} of 12
    // attention role
    const int hg = w >> 2;               // local head 0/1
    const int rs = w & 3;                // S row strip

    // stage rpb table + masks
    for (int i = t; i < 1800; i += 512) rpb_l[i] = rpb_table[i];
    if (t < 64) mask_l[t] = masks[(size_t)b * 64 + t];
    __syncthreads();

    const float* xp = x + (size_t)b * (NT * DIMC);
    const unsigned short* xh = xsh + (size_t)b * (NT * DIMC);
    const unsigned short* xl_ = xsl + (size_t)b * (NT * DIMC);
    float* op = aout + (size_t)b * (NT * DIMC);

    for (int pass = 0; pass < 4; ++pass) {
        // ---- phase 1: qkv GEMM for heads (2*pass, 2*pass+1) ----
        f32x4 acc[3][2];
        #pragma unroll
        for (int c = 0; c < 3; ++c) {
            const int pc = g_pc0 + c, mat = pc >> 2, within = pc & 3;
            const float bv = qkv_b[mat * 256 + (4 * pass + within) * 16 + l15];
            acc[c][0] = (f32x4){bv, bv, bv, bv};
            acc[c][1] = (f32x4){bv, bv, bv, bv};
        }
        for (int ks = 0; ks < 8; ++ks) {
            bf16x8 ah0, al0, ah1, al1;
            const int a0 = (g_rt0 * 16 + l15) * 256 + ks * 32 + lg * 8;
            const int a1 = a0 + 16 * 256;
            if (MODE == 0) {
                float av0[8], av1[8];
                *reinterpret_cast<float4*>(&av0[0]) = *reinterpret_cast<const float4*>(xp + a0);
                *reinterpret_cast<float4*>(&av0[4]) = *reinterpret_cast<const float4*>(xp + a0 + 4);
                *reinterpret_cast<float4*>(&av1[0]) = *reinterpret_cast<const float4*>(xp + a1);
                *reinterpret_cast<float4*>(&av1[4]) = *reinterpret_cast<const float4*>(xp + a1 + 4);
                cvt8(av0, ah0, al0);
                cvt8(av1, ah1, al1);
            } else {
                ah0 = *reinterpret_cast<const bf16x8*>(xh + a0);
                al0 = *reinterpret_cast<const bf16x8*>(xl_ + a0);
                ah1 = *reinterpret_cast<const bf16x8*>(xh + a1);
                al1 = *reinterpret_cast<const bf16x8*>(xl_ + a1);
            }
            #pragma unroll
            for (int c = 0; c < 3; ++c) {
                const int pc = g_pc0 + c, mat = pc >> 2, within = pc & 3;
                const int ct = mat * 16 + 4 * pass + within;
                const bf16x8 bh = *reinterpret_cast<const bf16x8*>(wqhi + ct * 4096 + ks * 512 + l * 8);
                const bf16x8 bl = *reinterpret_cast<const bf16x8*>(wqlo + ct * 4096 + ks * 512 + l * 8);
                acc[c][0] = MFMA16(ah0, bh, acc[c][0], 0, 0, 0);
                acc[c][0] = MFMA16(ah0, bl, acc[c][0], 0, 0, 0);
                acc[c][0] = MFMA16(al0, bh, acc[c][0], 0, 0, 0);
                acc[c][1] = MFMA16(ah1, bh, acc[c][1], 0, 0, 0);
                acc[c][1] = MFMA16(ah1, bl, acc[c][1], 0, 0, 0);
                acc[c][1] = MFMA16(al1, bh, acc[c][1], 0, 0, 0);
            }
        }
        // write q/k (row-major, +SCALE on q) and v transposed, all bf16 hi/lo
        #pragma unroll
        for (int c = 0; c < 3; ++c) {
            const int pc = g_pc0 + c, mat = pc >> 2, within = pc & 3;
            const int hh = within >> 1, dh = within & 1;
            #pragma unroll
            for (int rtl = 0; rtl < 2; ++rtl) {
                const int tok0 = (g_rt0 + rtl) * 16 + 4 * lg;
                #pragma unroll
                for (int r = 0; r < 4; ++r) {
                    float val = acc[c][rtl][r];
                    const int tok = tok0 + r;
                    if (mat == 0) {
                        val *= SCALE_;
                        const unsigned short hv = f2bf(val);
                        qhi[tok * 72 + hh * 32 + dh * 16 + l15] = hv;
                        qlo[tok * 72 + hh * 32 + dh * 16 + l15] = f2bf(val - bf2f(hv));
                    } else if (mat == 1) {
                        const unsigned short hv = f2bf(val);
                        khi[tok * 72 + hh * 32 + dh * 16 + l15] = hv;
                        klo[tok * 72 + hh * 32 + dh * 16 + l15] = f2bf(val - bf2f(hv));
                    } else {
                        const int d = dh * 16 + l15;
                        const unsigned short hv = f2bf(val);
                        vThi[hh * 2304 + d * 72 + tok] = hv;
                        vTlo[hh * 2304 + d * 72 + tok] = f2bf(val - bf2f(hv));
                    }
                }
            }
        }
        __syncthreads();   // (1) q/k/vT ready

        // ---- phase 2: QK^T (head h = 2*pass + hg, rows rs*16..+16) ----
        const int h = 2 * pass + hg;
        const bf16x8 aqh = *reinterpret_cast<const bf16x8*>(&qhi[(rs * 16 + l15) * 72 + hg * 32 + lg * 8]);
        const bf16x8 aql = *reinterpret_cast<const bf16x8*>(&qlo[(rs * 16 + l15) * 72 + hg * 32 + lg * 8]);
        f32x4 s[4];
        #pragma unroll
        for (int cs = 0; cs < 4; ++cs) {
            const bf16x8 bkh = *reinterpret_cast<const bf16x8*>(&khi[(cs * 16 + l15) * 72 + hg * 32 + lg * 8]);
            const bf16x8 bkl = *reinterpret_cast<const bf16x8*>(&klo[(cs * 16 + l15) * 72 + hg * 32 + lg * 8]);
            f32x4 z = (f32x4){0.f, 0.f, 0.f, 0.f};
            z = MFMA16(aqh, bkh, z, 0, 0, 0);
            z = MFMA16(aqh, bkl, z, 0, 0, 0);
            z = MFMA16(aql, bkh, z, 0, 0, 0);
            s[cs] = z;
        }
        // modulation + rpb + softmax (exact fp32 semantics)
        const int srow0 = rs * 16 + 4 * lg;
        unsigned long long mw[4];
        #pragma unroll
        for (int r = 0; r < 4; ++r) mw[r] = mask_l[srow0 + r];
        float pbuf[4][4], mx[4], sm[4], inv[4];
        #pragma unroll
        for (int r = 0; r < 4; ++r) mx[r] = -1e30f;
        #pragma unroll
        for (int cs = 0; cs < 4; ++cs) {
            const int scol = cs * 16 + l15;
            #pragma unroll
            for (int r = 0; r < 4; ++r) {
                const int srow = srow0 + r;
                float sv = s[cs][r];
                sv *= ((mw[r] >> scol) & 1ull) ? 1.0f : 1.2f;
                const int ridx = ((srow >> 3) - (scol >> 3) + 7) * 15 + ((srow & 7) - (scol & 7) + 7);
                sv += rpb_l[ridx * NHEADS + h];
                pbuf[r][cs] = sv;
                mx[r] = fmaxf(mx[r], sv);
            }
        }
        #pragma unroll
        for (int r = 0; r < 4; ++r) {
            mx[r] = fmaxf(mx[r], __shfl_xor(mx[r], 1));
            mx[r] = fmaxf(mx[r], __shfl_xor(mx[r], 2));
            mx[r] = fmaxf(mx[r], __shfl_xor(mx[r], 4));
            mx[r] = fmaxf(mx[r], __shfl_xor(mx[r], 8));
            sm[r] = 0.f;
        }
        #pragma unroll
        for (int cs = 0; cs < 4; ++cs)
            #pragma unroll
            for (int r = 0; r < 4; ++r) {
                pbuf[r][cs] = __expf(pbuf[r][cs] - mx[r]);
                sm[r] += pbuf[r][cs];
            }
        #pragma unroll
        for (int r = 0; r < 4; ++r) {
            sm[r] += __shfl_xor(sm[r], 1);
            sm[r] += __shfl_xor(sm[r], 2);
            sm[r] += __shfl_xor(sm[r], 4);
            sm[r] += __shfl_xor(sm[r], 8);
            inv[r] = 1.f / sm[r];
        }
        __syncthreads();   // (2) q/k reads done; P may overwrite that space

        #pragma unroll
        for (int cs = 0; cs < 4; ++cs) {
            const int scol = cs * 16 + l15;
            #pragma unroll
            for (int r = 0; r < 4; ++r) {
                const float pp = pbuf[r][cs] * inv[r];
                const unsigned short ph = f2bf(pp);
                phi[hg * 4608 + (srow0 + r) * 72 + scol] = ph;
                plo[hg * 4608 + (srow0 + r) * 72 + scol] = f2bf(pp - bf2f(ph));
            }
        }
        __syncthreads();   // (3) P ready

        // ---- phase 3: PV (out rows rs*16..+16, head h) -> global attn-out ----
        #pragma unroll
        for (int dt = 0; dt < 2; ++dt) {
            f32x4 o_ = (f32x4){0.f, 0.f, 0.f, 0.f};
            #pragma unroll
            for (int k2 = 0; k2 < 2; ++k2) {
                const bf16x8 pah = *reinterpret_cast<const bf16x8*>(&phi[hg * 4608 + (rs * 16 + l15) * 72 + k2 * 32 + lg * 8]);
                const bf16x8 pal = *reinterpret_cast<const bf16x8*>(&plo[hg * 4608 + (rs * 16 + l15) * 72 + k2 * 32 + lg * 8]);
                const bf16x8 vbh = *reinterpret_cast<const bf16x8*>(&vThi[hg * 2304 + (dt * 16 + l15) * 72 + k2 * 32 + lg * 8]);
                const bf16x8 vbl = *reinterpret_cast<const bf16x8*>(&vTlo[hg * 2304 + (dt * 16 + l15) * 72 + k2 * 32 + lg * 8]);
                o_ = MFMA16(pah, vbh, o_, 0, 0, 0);
                o_ = MFMA16(pah, vbl, o_, 0, 0, 0);
                o_ = MFMA16(pal, vbh, o_, 0, 0, 0);
            }
            #pragma unroll
            for (int r = 0; r < 4; ++r)
                op[(srow0 + r) * 256 + h * 32 + dt * 16 + l15] = o_[r];
        }
        __syncthreads();   // (4) p/vT reads done before next pass overwrites
    }
}

// ---------------- kernel 3: out projection via split-bf16 MFMA, in-place (r4-verified) ----------------
__global__ __launch_bounds__(512) void k_proj(
    const float* __restrict__ proj_b,
    const unsigned short* __restrict__ wphi,
    const unsigned short* __restrict__ wplo,
    float* __restrict__ inout)
{
    __shared__ alignas(16) unsigned short ahi[64][264];
    __shared__ alignas(16) unsigned short alo[64][264];
    const int b = blockIdx.x, t = threadIdx.x;
    const int l = t & 63;
    const int wave = __builtin_amdgcn_readfirstlane(t >> 6);

    float* base = inout + (size_t)b * (NT * DIMC);
    #pragma unroll
    for (int i = 0; i < 8; ++i) {
        int idx = t + i * 512;
        float4 v = reinterpret_cast<const float4*>(base)[idx];
        int n = idx >> 6, kq = (idx & 63) << 2;
        ushort4 h, lo;
        cvt4(v, h, lo);
        *reinterpret_cast<ushort4*>(&ahi[n][kq]) = h;
        *reinterpret_cast<ushort4*>(&alo[n][kq]) = lo;
    }
    __syncthreads();

    const int kgrp = 8 * (l >> 4);
    f32x4 acc[2][4];                      // [ct-local][rt]
    #pragma unroll
    for (int c = 0; c < 2; ++c) {
        const int col = (2 * wave + c) * 16 + (l & 15);
        const float bv = proj_b[col];
        #pragma unroll
        for (int r = 0; r < 4; ++r) acc[c][r] = (f32x4){bv, bv, bv, bv};
    }
    for (int ks = 0; ks < 8; ++ks) {
        bf16x8 ah0 = *reinterpret_cast<const bf16x8*>(&ahi[ 0 + (l & 15)][ks * 32 + kgrp]);
        bf16x8 al0 = *reinterpret_cast<const bf16x8*>(&alo[ 0 + (l & 15)][ks * 32 + kgrp]);
        bf16x8 ah1 = *reinterpret_cast<const bf16x8*>(&ahi[16 + (l & 15)][ks * 32 + kgrp]);
        bf16x8 al1 = *reinterpret_cast<const bf16x8*>(&alo[16 + (l & 15)][ks * 32 + kgrp]);
        bf16x8 ah2 = *reinterpret_cast<const bf16x8*>(&ahi[32 + (l & 15)][ks * 32 + kgrp]);
        bf16x8 al2 = *reinterpret_cast<const bf16x8*>(&alo[32 + (l & 15)][ks * 32 + kgrp]);
        bf16x8 ah3 = *reinterpret_cast<const bf16x8*>(&ahi[48 + (l & 15)][ks * 32 + kgrp]);
        bf16x8 al3 = *reinterpret_cast<const bf16x8*>(&alo[48 + (l & 15)][ks * 32 + kgrp]);
        #pragma unroll
        for (int c = 0; c < 2; ++c) {
            const int ct = 2 * wave + c;
            const int off = ct * 4096 + ks * 512 + l * 8;
            const bf16x8 bh = *reinterpret_cast<const bf16x8*>(wphi + off);
            const bf16x8 bl = *reinterpret_cast<const bf16x8*>(wplo + off);
            acc[c][0] = MFMA16(ah0, bh, acc[c][0], 0, 0, 0);
            acc[c][0] = MFMA16(ah0, bl, acc[c][0], 0, 0, 0);
            acc[c][0] = MFMA16(al0, bh, acc[c][0], 0, 0, 0);
            acc[c][1] = MFMA16(ah1, bh, acc[c][1], 0, 0, 0);
            acc[c][1] = MFMA16(ah1, bl, acc[c][1], 0, 0, 0);
            acc[c][1] = MFMA16(al1, bh, acc[c][1], 0, 0, 0);
            acc[c][2] = MFMA16(ah2, bh, acc[c][2], 0, 0, 0);
            acc[c][2] = MFMA16(ah2, bl, acc[c][2], 0, 0, 0);
            acc[c][2] = MFMA16(al2, bh, acc[c][2], 0, 0, 0);
            acc[c][3] = MFMA16(ah3, bh, acc[c][3], 0, 0, 0);
            acc[c][3] = MFMA16(ah3, bl, acc[c][3], 0, 0, 0);
            acc[c][3] = MFMA16(al3, bh, acc[c][3], 0, 0, 0);
        }
    }
    {
        const int rowo = 4 * (l >> 4);
        #pragma unroll
        for (int c = 0; c < 2; ++c) {
            const int col = (2 * wave + c) * 16 + (l & 15);
            #pragma unroll
            for (int rt = 0; rt < 4; ++rt) {
                #pragma unroll
                for (int r = 0; r < 4; ++r)
                    base[(rt * 16 + rowo + r) * 256 + col] = acc[c][rt][r];
            }
        }
    }
}

extern "C" void kernel_launch(void* const* d_in, const int* in_sizes, int n_in,
                              void* d_out, int out_size, void* d_ws, size_t ws_size,
                              hipStream_t stream)
{
    const float* x      = (const float*)d_in[0];
    const float* var    = (const float*)d_in[1];
    const float* qkv_w  = (const float*)d_in[2];
    const float* qkv_b  = (const float*)d_in[3];
    const float* proj_w = (const float*)d_in[4];
    const float* proj_b = (const float*)d_in[5];
    const float* rpb    = (const float*)d_in[6];
    float* out = (float*)d_out;

    unsigned short* wqhi = (unsigned short*)d_ws;          // 196608
    unsigned short* wqlo = wqhi + 196608;                  // 196608
    unsigned short* wphi = wqlo + 196608;                  // 65536
    unsigned short* wplo = wphi + 65536;                   // 65536
    unsigned long long* masks = (unsigned long long*)((char*)d_ws + 1048576);
    unsigned short* xsh = (unsigned short*)((char*)d_ws + 2097152);
    unsigned short* xsl = xsh + 33554432;

    const bool presplit = (ws_size >= PRESPLIT_NEED);

    k_prep      <<<1024, 256, 0, stream>>>(qkv_w, proj_w, wqhi, wqlo, wphi, wplo);
    k_modulation<<<NWIN, 512, 0, stream>>>(var, masks);
    if (presplit) {
        k_xsplit <<<4096, 256, 0, stream>>>(x, xsh, xsl);
        k_attn<1><<<NWIN, 512, 0, stream>>>(x, xsh, xsl, qkv_b, rpb, wqhi, wqlo, masks, out);
    } else {
        k_attn<0><<<NWIN, 512, 0, stream>>>(x, xsh, xsl, qkv_b, rpb, wqhi, wqlo, masks, out);
    }
    k_proj      <<<NWIN, 512, 0, stream>>>(proj_b, wphi, wplo, out);
}